// Round 17
// baseline (260.624 us; speedup 1.0000x reference)
//
#include <hip/hip_runtime.h>
#include <math.h>

#define NN 100000
#define NE 1600000
#define NBINS 391          // bin = dst >> 8
#define BCAP 4608          // padded bin capacity (mean 4092, sigma 64 -> +8 sigma)
#define EB   782           // edge-scatter blocks (2048 edges each)
#define CVT_B 6250         // cvt blocks (x -> bf16 + fp8)
// IN = HID = 64, OUT = 40

typedef unsigned long long ull;
typedef float f32x4 __attribute__((ext_vector_type(4)));
typedef float f32x2 __attribute__((ext_vector_type(2)));
typedef short s16x8 __attribute__((ext_vector_type(8)));

__device__ __forceinline__ unsigned short f2bf(float f) {
    unsigned b = __float_as_uint(f);
    return (unsigned short)((b + 0x7fffu + ((b >> 16) & 1u)) >> 16);
}
__device__ __forceinline__ unsigned pack4_fp8(float a, float b, float c, float d) {
    int r = 0;
    r = __builtin_amdgcn_cvt_pk_fp8_f32(a, b, r, false);
    r = __builtin_amdgcn_cvt_pk_fp8_f32(c, d, r, true);
    return (unsigned)r;
}

// ---------------------------------------------------------------------------
// merged prep + p3:
//  [0, EB): edge scatter -> brec4 grouped by padded bin (LDS reorder).
//           buf record (ull) = dst17<<24 | u7<<17 | src17; global record (u32)
//           = dst_low8<<24 | u7<<17 | src17. binCur[b] = count (memset 0).
//  [EB, EB+CVT_B): x -> xbf (bf16) + x8 (fp8)
//  [+6): pack W1|root1 -> Bp1   [+5): pack W2|root2 -> Bp2
// ---------------------------------------------------------------------------
__global__ __launch_bounds__(256) void prep_p3_kernel(
        const int* __restrict__ src, const int* __restrict__ dst,
        const float* __restrict__ u, int* __restrict__ binCur,
        unsigned* __restrict__ brec4,
        const float* __restrict__ x, unsigned short* __restrict__ xbf,
        unsigned* __restrict__ x8,
        const float* __restrict__ W1, const float* __restrict__ root1,
        unsigned short* __restrict__ Bp1,
        const float* __restrict__ W2, const float* __restrict__ root2,
        unsigned short* __restrict__ Bp2) {
    __shared__ int cnt[512], lstart[512], gbase[512], lcur[512];
    __shared__ int sa[512], sb[512];
    __shared__ ull buf[2048];
    const int b = blockIdx.x;
    const int t = threadIdx.x;
    if (b < EB) {
        cnt[t] = 0; cnt[t + 256] = 0;
        __syncthreads();
        const int base = b * 2048;
        int mysrc[8], mydst[8];
        float myu[8];
        #pragma unroll
        for (int k = 0; k < 8; ++k) {
            const int i = base + k * 256 + t;
            if (i < NE) {
                mydst[k] = dst[i]; mysrc[k] = src[i]; myu[k] = u[i];
                atomicAdd(&cnt[mydst[k] >> 8], 1);
            } else {
                mydst[k] = -1;
            }
        }
        __syncthreads();
        sa[t] = cnt[t]; sa[t + 256] = cnt[t + 256];
        __syncthreads();
        int* cur = sa; int* nxt = sb;
        for (int off = 1; off < 512; off <<= 1) {
            for (int j = t; j < 512; j += 256)
                nxt[j] = cur[j] + ((j >= off) ? cur[j - off] : 0);
            __syncthreads();
            int* tmp = cur; cur = nxt; nxt = tmp;
        }
        for (int j = t; j < 512; j += 256) {
            const int ex = (j == 0) ? 0 : cur[j - 1];
            lstart[j] = ex;
            lcur[j]   = ex;
        }
        __syncthreads();
        for (int j = t; j < 512; j += 256) {
            const int c = cnt[j];
            gbase[j] = c ? (j * BCAP + atomicAdd(&binCur[j], c)) : 0;
        }
        #pragma unroll
        for (int k = 0; k < 8; ++k) {
            if (mydst[k] >= 0) {
                const int bb = mydst[k] >> 8;
                const int lp = atomicAdd(&lcur[bb], 1);
                int uq = (int)(myu[k] * 128.0f + 0.5f);
                if (uq > 127) uq = 127;
                buf[lp] = ((ull)(unsigned)mydst[k] << 24) |
                          ((unsigned)uq << 17) | (unsigned)mysrc[k];
            }
        }
        __syncthreads();
        const int total = lstart[511] + cnt[511];
        for (int i = t; i < total; i += 256) {
            const ull r = buf[i];
            const int d  = (int)(r >> 24);       // full dst (17b)
            const int bb = d >> 8;
            brec4[(size_t)(gbase[bb] + (i - lstart[bb]))] =
                ((unsigned)(d & 0xFF) << 24) | (unsigned)(r & 0xFFFFFFu);
        }
    } else if (b < EB + CVT_B) {
        const int i = (b - EB) * 256 + t;
        if (i < NN * 16) {
            const float4 v = ((const float4*)x)[i];
            ushort4 q;
            q.x = f2bf(v.x); q.y = f2bf(v.y); q.z = f2bf(v.z); q.w = f2bf(v.w);
            ((ushort4*)xbf)[i] = q;
            x8[i] = pack4_fp8(v.x, v.y, v.z, v.w);
        }
    } else if (b < EB + CVT_B + 6) {
        const int gid = (b - EB - CVT_B) * 256 + t;
        if (gid < 6 * 4 * 64) {
            const int kb = gid >> 8;
            const int ct = (gid >> 6) & 3;
            const int l  = gid & 63;
            const int n  = ct * 16 + (l & 15);
            const int k0 = kb * 32 + (l >> 4) * 8;
            #pragma unroll
            for (int j = 0; j < 8; ++j) {
                const int k = k0 + j;
                const float v = (k < 128) ? W1[k * 64 + n] : root1[(k - 128) * 64 + n];
                Bp1[gid * 8 + j] = f2bf(v);
            }
        }
    } else {
        const int gid = (b - EB - CVT_B - 6) * 256 + t;
        if (gid < 6 * 3 * 64) {
            const int kb = gid / 192;
            const int r  = gid - kb * 192;
            const int ct = r >> 6;
            const int l  = r & 63;
            const int n  = ct * 16 + (l & 15);
            const int k0 = kb * 32 + (l >> 4) * 8;
            #pragma unroll
            for (int j = 0; j < 8; ++j) {
                const int k = k0 + j;
                float v = 0.f;
                if (n < 40) v = (k < 128) ? W2[k * 40 + n] : root2[(k - 128) * 40 + n];
                Bp2[gid * 8 + j] = f2bf(v);
            }
        }
    }
}

// ---------------------------------------------------------------------------
// p4: per-bin finalize: deg + rowstart + CSR scatter with LDS cursors.
// Bin b occupies brec4[b*BCAP .. b*BCAP+binCur[b]). rec4 = u7<<17 | src17.
// ---------------------------------------------------------------------------
__global__ __launch_bounds__(256) void p4_final_kernel(
        const unsigned* __restrict__ brec4, const int* __restrict__ binCur,
        int* __restrict__ deg, int* __restrict__ rowstart,
        unsigned* __restrict__ rec4) {
    __shared__ int cnt[256], lpos[256], wsum[4];
    const int b = blockIdx.x;
    const int s = b * BCAP, e = s + binCur[b];
    const int t = threadIdx.x;
    cnt[t] = 0;
    __syncthreads();
    for (int i = s + t; i < e; i += 256)
        atomicAdd(&cnt[brec4[i] >> 24], 1);
    __syncthreads();
    const int lane = t & 63, w = t >> 6;
    const int v = cnt[t];
    int inc = v;
    for (int off = 1; off < 64; off <<= 1) {
        int tv = __shfl_up(inc, off, 64);
        if (lane >= off) inc += tv;
    }
    if (lane == 63) wsum[w] = inc;
    __syncthreads();
    int add = 0;
    #pragma unroll
    for (int i = 0; i < 4; ++i) if (i < w) add += wsum[i];
    const int excl = add + inc - v;
    const int node = b * 256 + t;
    if (node < NN) {
        deg[node]      = v;
        rowstart[node] = s + excl;
    }
    lpos[t] = s + excl;
    __syncthreads();
    for (int i = s + t; i < e; i += 256) {
        const unsigned r = brec4[i];
        const int p = atomicAdd(&lpos[r >> 24], 1);
        rec4[p] = r & 0x00FFFFFFu;
    }
}

// ---------------------------------------------------------------------------
// fused layer, 1 wave per 16-node tile, fp8 gather with 4 lanes/node (uint4
// 16B loads): ONE pass, 16 concurrent nodes per wave -> minimum serial steps.
// Aggregates into a 4KB XOR-swizzled LDS tile, drains own DS queue, MFMAs.
// LAYER1: hbf = elu([A|x]@Bp1 + b1), also emits h8 (fp8) for layer-2 gather.
// LAYER2: out = log_softmax([A|h]@Bp2 + b2)
// ---------------------------------------------------------------------------
template <int LAYER>
__global__ __launch_bounds__(64, 6) void fused_kernel(
        const int* __restrict__ rowstart, const int* __restrict__ deg,
        const unsigned* __restrict__ rec4, const unsigned* __restrict__ feat8,
        const unsigned short* __restrict__ featb,
        const s16x8* __restrict__ Bp, const float* __restrict__ bias,
        unsigned short* __restrict__ hbf, unsigned char* __restrict__ h8,
        float* __restrict__ out) {
    __shared__ __align__(16) unsigned char sW[16 * 256];   // 4 KB per wave
    const int l = threadIdx.x;
    const int base = blockIdx.x * 16;
    const uint4* __restrict__ f8v = (const uint4*)feat8;   // row = 4 x uint4
    const float UQS = 1.0f / 128.0f;

    // ---- gather phase: single pass, 16 concurrent nodes (4 lanes each) ----
    {
        const int nlq = l >> 2;     // node slot 0..15
        const int f   = l & 3;      // uint4 feature slot (16 feats)
        const int node = base + nlq;
        int dg = 0, st = 0;
        if (node < NN) { dg = deg[node]; st = rowstart[node]; }
        float sum[16], smu[16];
        #pragma unroll
        for (int k = 0; k < 16; ++k) { sum[k] = 0.f; smu[k] = 0.f; }

#define EDGE_BODY(IDX)                                                         \
        {                                                                      \
            const unsigned r = rec4[(size_t)(st + (IDX))];                     \
            const float u2 = (float)((r >> 17) & 0x7Fu) * UQS;                 \
            const uint4 q = f8v[(size_t)(r & 0x1FFFFu) * 4 + f];               \
            const f32x2 d0 = __builtin_amdgcn_cvt_pk_f32_fp8((int)q.x, false); \
            const f32x2 d1 = __builtin_amdgcn_cvt_pk_f32_fp8((int)q.x, true);  \
            const f32x2 d2 = __builtin_amdgcn_cvt_pk_f32_fp8((int)q.y, false); \
            const f32x2 d3 = __builtin_amdgcn_cvt_pk_f32_fp8((int)q.y, true);  \
            const f32x2 d4 = __builtin_amdgcn_cvt_pk_f32_fp8((int)q.z, false); \
            const f32x2 d5 = __builtin_amdgcn_cvt_pk_f32_fp8((int)q.z, true);  \
            const f32x2 d6 = __builtin_amdgcn_cvt_pk_f32_fp8((int)q.w, false); \
            const f32x2 d7 = __builtin_amdgcn_cvt_pk_f32_fp8((int)q.w, true);  \
            sum[0]  += d0[0]; smu[0]  = fmaf(u2, d0[0], smu[0]);               \
            sum[1]  += d0[1]; smu[1]  = fmaf(u2, d0[1], smu[1]);               \
            sum[2]  += d1[0]; smu[2]  = fmaf(u2, d1[0], smu[2]);               \
            sum[3]  += d1[1]; smu[3]  = fmaf(u2, d1[1], smu[3]);               \
            sum[4]  += d2[0]; smu[4]  = fmaf(u2, d2[0], smu[4]);               \
            sum[5]  += d2[1]; smu[5]  = fmaf(u2, d2[1], smu[5]);               \
            sum[6]  += d3[0]; smu[6]  = fmaf(u2, d3[0], smu[6]);               \
            sum[7]  += d3[1]; smu[7]  = fmaf(u2, d3[1], smu[7]);               \
            sum[8]  += d4[0]; smu[8]  = fmaf(u2, d4[0], smu[8]);               \
            sum[9]  += d4[1]; smu[9]  = fmaf(u2, d4[1], smu[9]);               \
            sum[10] += d5[0]; smu[10] = fmaf(u2, d5[0], smu[10]);              \
            sum[11] += d5[1]; smu[11] = fmaf(u2, d5[1], smu[11]);              \
            sum[12] += d6[0]; smu[12] = fmaf(u2, d6[0], smu[12]);              \
            sum[13] += d6[1]; smu[13] = fmaf(u2, d6[1], smu[13]);              \
            sum[14] += d7[0]; smu[14] = fmaf(u2, d7[0], smu[14]);              \
            sum[15] += d7[1]; smu[15] = fmaf(u2, d7[1], smu[15]);              \
        }

        int i = 0;
        for (; i + 4 <= dg; i += 4) {
            EDGE_BODY(i + 0)
            EDGE_BODY(i + 1)
            EDGE_BODY(i + 2)
            EDGE_BODY(i + 3)
        }
        for (; i < dg; ++i) {
            EDGE_BODY(i)
        }
#undef EDGE_BODY

        const float inv = 1.0f / fmaxf((float)dg, 1.0f);
        s16x8 p0a, p0b, p1a, p1b;
        #pragma unroll
        for (int k = 0; k < 8; ++k) {
            p0a[k] = (short)f2bf((sum[k] - smu[k]) * inv);
            p0b[k] = (short)f2bf((sum[k + 8] - smu[k + 8]) * inv);
            p1a[k] = (short)f2bf(smu[k] * inv);
            p1b[k] = (short)f2bf(smu[k + 8] * inv);
        }
        const int swz = (nlq & 7) << 4;
        unsigned char* rowp = sW + nlq * 256;
        *(s16x8*)(rowp + ((f * 32) ^ swz))            = p0a;
        *(s16x8*)(rowp + ((f * 32 + 16) ^ swz))       = p0b;
        *(s16x8*)(rowp + 128 + ((f * 32) ^ swz))      = p1a;
        *(s16x8*)(rowp + 128 + ((f * 32 + 16) ^ swz)) = p1b;
    }
    // wave-local drain of own DS queue; fence scheduler (guide rule #18).
    asm volatile("s_waitcnt lgkmcnt(0)" ::: "memory");
    __builtin_amdgcn_sched_barrier(0);

    // ---- MFMA phase: this wave's 16 rows ----
    const int kg = l >> 4;
    const int rl = l & 15;                    // row within wave tile
    const int swzr = (rl & 7) << 4;
    int grow = base + rl;
    if (grow >= NN) grow = NN - 1;
    const s16x8* __restrict__ Xr = (const s16x8*)(featb + (size_t)grow * 64);

    s16x8 af[6];
    #pragma unroll
    for (int kb = 0; kb < 2; ++kb)
        af[kb] = *(const s16x8*)(sW + rl * 256 + ((kb * 64 + kg * 16) ^ swzr));
    #pragma unroll
    for (int kb = 2; kb < 4; ++kb)
        af[kb] = *(const s16x8*)(sW + rl * 256 + 128 + (((kb - 2) * 64 + kg * 16) ^ swzr));
    af[4] = Xr[kg];
    af[5] = Xr[4 + kg];

    if (LAYER == 1) {
        f32x4 acc[4];
        #pragma unroll
        for (int ct = 0; ct < 4; ++ct) acc[ct] = (f32x4){0.f, 0.f, 0.f, 0.f};
        #pragma unroll
        for (int kb = 0; kb < 6; ++kb) {
            #pragma unroll
            for (int ct = 0; ct < 4; ++ct) {
                acc[ct] = __builtin_amdgcn_mfma_f32_16x16x32_bf16(
                    af[kb], Bp[(kb * 4 + ct) * 64 + l], acc[ct], 0, 0, 0);
            }
        }
        const int orow0 = base + kg * 4;
        #pragma unroll
        for (int ct = 0; ct < 4; ++ct) {
            const float bv = bias[ct * 16 + (l & 15)];
            #pragma unroll
            for (int j = 0; j < 4; ++j) {
                float v = acc[ct][j] + bv;
                v = (v > 0.f) ? v : (__expf(v) - 1.f);
                const int r2 = orow0 + j;
                if (r2 < NN) {
                    hbf[(size_t)r2 * 64 + ct * 16 + (l & 15)] = f2bf(v);
                    const int e8 = __builtin_amdgcn_cvt_pk_fp8_f32(v, v, 0, false);
                    h8[(size_t)r2 * 64 + ct * 16 + (l & 15)] = (unsigned char)(e8 & 0xFF);
                }
            }
        }
    } else {
        f32x4 acc[3];
        #pragma unroll
        for (int ct = 0; ct < 3; ++ct) acc[ct] = (f32x4){0.f, 0.f, 0.f, 0.f};
        #pragma unroll
        for (int kb = 0; kb < 6; ++kb) {
            #pragma unroll
            for (int ct = 0; ct < 3; ++ct) {
                acc[ct] = __builtin_amdgcn_mfma_f32_16x16x32_bf16(
                    af[kb], Bp[(kb * 3 + ct) * 64 + l], acc[ct], 0, 0, 0);
            }
        }
        const int col = l & 15;
        const float b0 = bias[col], b1v = bias[16 + col];
        const float b2v = (col < 8) ? bias[32 + col] : 0.f;
        #pragma unroll
        for (int j = 0; j < 4; ++j) {
            const float v0 = acc[0][j] + b0;
            const float v1 = acc[1][j] + b1v;
            const float v2 = (col < 8) ? (acc[2][j] + b2v) : -3.0e38f;
            float m = fmaxf(fmaxf(v0, v1), v2);
            #pragma unroll
            for (int off = 1; off < 16; off <<= 1) m = fmaxf(m, __shfl_xor(m, off, 64));
            float s = __expf(v0 - m) + __expf(v1 - m) + ((col < 8) ? __expf(v2 - m) : 0.f);
            #pragma unroll
            for (int off = 1; off < 16; off <<= 1) s += __shfl_xor(s, off, 64);
            const float lse = m + __logf(s);
            const int r2 = base + kg * 4 + j;
            if (r2 < NN) {
                float* __restrict__ orow = out + (size_t)r2 * 40;
                orow[col]      = v0 - lse;
                orow[16 + col] = v1 - lse;
                if (col < 8) orow[32 + col] = v2 - lse;
            }
        }
    }
}

// ---------------------------------------------------------------------------
extern "C" void kernel_launch(void* const* d_in, const int* in_sizes, int n_in,
                              void* d_out, int out_size, void* d_ws, size_t ws_size,
                              hipStream_t stream) {
    const float* x     = (const float*)d_in[0];
    const int*   ei    = (const int*)  d_in[1];
    const float* u     = (const float*)d_in[2];
    const float* W1    = (const float*)d_in[3];
    const float* root1 = (const float*)d_in[4];
    const float* b1    = (const float*)d_in[5];
    const float* W2    = (const float*)d_in[6];
    const float* root2 = (const float*)d_in[7];
    const float* b2    = (const float*)d_in[8];
    float*       out   = (float*)d_out;

    const int* src = ei;
    const int* dst = ei + NE;

    // ws layout (padded bins: brec4/rec4 sized NBINS*BCAP, 4B records)
    char* p = (char*)d_ws;
    int* binCur   = (int*)p;  p += 4 * 512;
    int* deg      = (int*)p;  p += (size_t)4 * NN;
    int* rowstart = (int*)p;  p += (size_t)4 * NN;
    unsigned* brec4 = (unsigned*)p;  p += (size_t)4 * NBINS * BCAP;
    unsigned* rec4  = (unsigned*)p;  p += (size_t)4 * NBINS * BCAP;
    unsigned short* xbf = (unsigned short*)p;  p += (size_t)2 * NN * 64;
    unsigned short* hbf = (unsigned short*)p;  p += (size_t)2 * NN * 64;
    unsigned* x8  = (unsigned*)p;  p += (size_t)4 * NN * 16;
    unsigned char* h8 = (unsigned char*)p;  p += (size_t)NN * 64;
    unsigned short* Bp1 = (unsigned short*)p;  p += (size_t)2 * 6 * 4 * 64 * 8;
    unsigned short* Bp2 = (unsigned short*)p;  p += (size_t)2 * 6 * 3 * 64 * 8;

    hipMemsetAsync(binCur, 0, 4 * 512, stream);

    prep_p3_kernel<<<EB + CVT_B + 11, 256, 0, stream>>>(
        src, dst, u, binCur, brec4,
        x, xbf, x8, W1, root1, Bp1, W2, root2, Bp2);
    p4_final_kernel<<<NBINS, 256, 0, stream>>>(brec4, binCur, deg, rowstart, rec4);

    const int NWB = (NN + 15) / 16;   // one wave (16 nodes) per block
    fused_kernel<1><<<NWB, 64, 0, stream>>>(rowstart, deg, rec4, x8, xbf,
                                            (const s16x8*)Bp1, b1, hbf, h8, nullptr);
    fused_kernel<2><<<NWB, 64, 0, stream>>>(rowstart, deg, rec4, (const unsigned*)h8, hbf,
                                            (const s16x8*)Bp2, b2, nullptr, nullptr, out);
}

// Round 18
// 120.699 us; speedup vs baseline: 2.1593x; 2.1593x over previous
//
#include <hip/hip_runtime.h>
#include <math.h>

#define NN 100000
#define NE 1600000
#define NBINS 391          // bin = dst >> 8
#define BCAP 4608          // padded bin capacity (mean 4092, sigma 64 -> +8 sigma)
#define EB   782           // edge-scatter blocks (2048 edges each)
#define CVT_B 6250         // cvt blocks (x -> bf16 + fp8)
// IN = HID = 64, OUT = 40

typedef unsigned long long ull;
typedef float f32x4 __attribute__((ext_vector_type(4)));
typedef float f32x2 __attribute__((ext_vector_type(2)));
typedef short s16x8 __attribute__((ext_vector_type(8)));

__device__ __forceinline__ unsigned short f2bf(float f) {
    unsigned b = __float_as_uint(f);
    return (unsigned short)((b + 0x7fffu + ((b >> 16) & 1u)) >> 16);
}
__device__ __forceinline__ unsigned pack4_fp8(float a, float b, float c, float d) {
    int r = 0;
    r = __builtin_amdgcn_cvt_pk_fp8_f32(a, b, r, false);
    r = __builtin_amdgcn_cvt_pk_fp8_f32(c, d, r, true);
    return (unsigned)r;
}

// ---------------------------------------------------------------------------
// merged prep + p3:
//  [0, EB): edge scatter -> brec4 grouped by padded bin (LDS reorder).
//           buf record (ull) = dst17<<24 | u7<<17 | src17; global record (u32)
//           = dst_low8<<24 | u7<<17 | src17. binCur[b] = count (memset 0).
//  [EB, EB+CVT_B): x -> xbf (bf16) + x8 (fp8)
//  [+6): pack W1|root1 -> Bp1   [+5): pack W2|root2 -> Bp2
// ---------------------------------------------------------------------------
__global__ __launch_bounds__(256) void prep_p3_kernel(
        const int* __restrict__ src, const int* __restrict__ dst,
        const float* __restrict__ u, int* __restrict__ binCur,
        unsigned* __restrict__ brec4,
        const float* __restrict__ x, unsigned short* __restrict__ xbf,
        unsigned* __restrict__ x8,
        const float* __restrict__ W1, const float* __restrict__ root1,
        unsigned short* __restrict__ Bp1,
        const float* __restrict__ W2, const float* __restrict__ root2,
        unsigned short* __restrict__ Bp2) {
    __shared__ int cnt[512], lstart[512], gbase[512], lcur[512];
    __shared__ int sa[512], sb[512];
    __shared__ ull buf[2048];
    const int b = blockIdx.x;
    const int t = threadIdx.x;
    if (b < EB) {
        cnt[t] = 0; cnt[t + 256] = 0;
        __syncthreads();
        const int base = b * 2048;
        int mysrc[8], mydst[8];
        float myu[8];
        #pragma unroll
        for (int k = 0; k < 8; ++k) {
            const int i = base + k * 256 + t;
            if (i < NE) {
                mydst[k] = dst[i]; mysrc[k] = src[i]; myu[k] = u[i];
                atomicAdd(&cnt[mydst[k] >> 8], 1);
            } else {
                mydst[k] = -1;
            }
        }
        __syncthreads();
        sa[t] = cnt[t]; sa[t + 256] = cnt[t + 256];
        __syncthreads();
        int* cur = sa; int* nxt = sb;
        for (int off = 1; off < 512; off <<= 1) {
            for (int j = t; j < 512; j += 256)
                nxt[j] = cur[j] + ((j >= off) ? cur[j - off] : 0);
            __syncthreads();
            int* tmp = cur; cur = nxt; nxt = tmp;
        }
        for (int j = t; j < 512; j += 256) {
            const int ex = (j == 0) ? 0 : cur[j - 1];
            lstart[j] = ex;
            lcur[j]   = ex;
        }
        __syncthreads();
        for (int j = t; j < 512; j += 256) {
            const int c = cnt[j];
            gbase[j] = c ? (j * BCAP + atomicAdd(&binCur[j], c)) : 0;
        }
        #pragma unroll
        for (int k = 0; k < 8; ++k) {
            if (mydst[k] >= 0) {
                const int bb = mydst[k] >> 8;
                const int lp = atomicAdd(&lcur[bb], 1);
                int uq = (int)(myu[k] * 128.0f + 0.5f);
                if (uq > 127) uq = 127;
                buf[lp] = ((ull)(unsigned)mydst[k] << 24) |
                          ((unsigned)uq << 17) | (unsigned)mysrc[k];
            }
        }
        __syncthreads();
        const int total = lstart[511] + cnt[511];
        for (int i = t; i < total; i += 256) {
            const ull r = buf[i];
            const int d  = (int)(r >> 24);       // full dst (17b)
            const int bb = d >> 8;
            brec4[(size_t)(gbase[bb] + (i - lstart[bb]))] =
                ((unsigned)(d & 0xFF) << 24) | (unsigned)(r & 0xFFFFFFu);
        }
    } else if (b < EB + CVT_B) {
        const int i = (b - EB) * 256 + t;
        if (i < NN * 16) {
            const float4 v = ((const float4*)x)[i];
            ushort4 q;
            q.x = f2bf(v.x); q.y = f2bf(v.y); q.z = f2bf(v.z); q.w = f2bf(v.w);
            ((ushort4*)xbf)[i] = q;
            x8[i] = pack4_fp8(v.x, v.y, v.z, v.w);
        }
    } else if (b < EB + CVT_B + 6) {
        const int gid = (b - EB - CVT_B) * 256 + t;
        if (gid < 6 * 4 * 64) {
            const int kb = gid >> 8;
            const int ct = (gid >> 6) & 3;
            const int l  = gid & 63;
            const int n  = ct * 16 + (l & 15);
            const int k0 = kb * 32 + (l >> 4) * 8;
            #pragma unroll
            for (int j = 0; j < 8; ++j) {
                const int k = k0 + j;
                const float v = (k < 128) ? W1[k * 64 + n] : root1[(k - 128) * 64 + n];
                Bp1[gid * 8 + j] = f2bf(v);
            }
        }
    } else {
        const int gid = (b - EB - CVT_B - 6) * 256 + t;
        if (gid < 6 * 3 * 64) {
            const int kb = gid / 192;
            const int r  = gid - kb * 192;
            const int ct = r >> 6;
            const int l  = r & 63;
            const int n  = ct * 16 + (l & 15);
            const int k0 = kb * 32 + (l >> 4) * 8;
            #pragma unroll
            for (int j = 0; j < 8; ++j) {
                const int k = k0 + j;
                float v = 0.f;
                if (n < 40) v = (k < 128) ? W2[k * 40 + n] : root2[(k - 128) * 40 + n];
                Bp2[gid * 8 + j] = f2bf(v);
            }
        }
    }
}

// ---------------------------------------------------------------------------
// p4: per-bin finalize: deg + rowstart + CSR scatter with LDS cursors.
// Bin b occupies brec4[b*BCAP .. b*BCAP+binCur[b]). rec4 = u7<<17 | src17.
// ---------------------------------------------------------------------------
__global__ __launch_bounds__(256) void p4_final_kernel(
        const unsigned* __restrict__ brec4, const int* __restrict__ binCur,
        int* __restrict__ deg, int* __restrict__ rowstart,
        unsigned* __restrict__ rec4) {
    __shared__ int cnt[256], lpos[256], wsum[4];
    const int b = blockIdx.x;
    const int s = b * BCAP, e = s + binCur[b];
    const int t = threadIdx.x;
    cnt[t] = 0;
    __syncthreads();
    for (int i = s + t; i < e; i += 256)
        atomicAdd(&cnt[brec4[i] >> 24], 1);
    __syncthreads();
    const int lane = t & 63, w = t >> 6;
    const int v = cnt[t];
    int inc = v;
    for (int off = 1; off < 64; off <<= 1) {
        int tv = __shfl_up(inc, off, 64);
        if (lane >= off) inc += tv;
    }
    if (lane == 63) wsum[w] = inc;
    __syncthreads();
    int add = 0;
    #pragma unroll
    for (int i = 0; i < 4; ++i) if (i < w) add += wsum[i];
    const int excl = add + inc - v;
    const int node = b * 256 + t;
    if (node < NN) {
        deg[node]      = v;
        rowstart[node] = s + excl;
    }
    lpos[t] = s + excl;
    __syncthreads();
    for (int i = s + t; i < e; i += 256) {
        const unsigned r = brec4[i];
        const int p = atomicAdd(&lpos[r >> 24], 1);
        rec4[p] = r & 0x00FFFFFFu;
    }
}

// ---------------------------------------------------------------------------
// fused layer, 1 wave per 16-node tile, fp8 gather with 8 lanes/node (uint2
// loads): 2 passes x 8 concurrent nodes per wave (round-16 proven geometry,
// 16-float accumulator state -> no scratch spill). Aggregates into a 4KB
// XOR-swizzled LDS tile, drains own DS queue, then MFMAs.
// LAYER1: hbf = elu([A|x]@Bp1 + b1), also emits h8 (fp8) for layer-2 gather.
// LAYER2: out = log_softmax([A|h]@Bp2 + b2)
// ---------------------------------------------------------------------------
template <int LAYER>
__global__ __launch_bounds__(64, 8) void fused_kernel(
        const int* __restrict__ rowstart, const int* __restrict__ deg,
        const unsigned* __restrict__ rec4, const unsigned* __restrict__ feat8,
        const unsigned short* __restrict__ featb,
        const s16x8* __restrict__ Bp, const float* __restrict__ bias,
        unsigned short* __restrict__ hbf, unsigned char* __restrict__ h8,
        float* __restrict__ out) {
    __shared__ __align__(16) unsigned char sW[16 * 256];   // 4 KB per wave
    const int l = threadIdx.x;
    const int base = blockIdx.x * 16;
    const uint2* __restrict__ f8v = (const uint2*)feat8;   // row = 8 x uint2
    const float UQS = 1.0f / 128.0f;

    // ---- gather phase: 2 passes, 8 concurrent nodes per wave ----
    {
        const int grp = l >> 3;     // node slot 0..7
        const int f   = l & 7;      // uint2 feature slot (8 feats)
        #pragma unroll
        for (int pass = 0; pass < 2; ++pass) {
            const int nlq  = pass * 8 + grp;          // row within wave tile
            const int node = base + nlq;
            int dg = 0, st = 0;
            if (node < NN) { dg = deg[node]; st = rowstart[node]; }
            float sum[8], smu[8];
            #pragma unroll
            for (int k = 0; k < 8; ++k) { sum[k] = 0.f; smu[k] = 0.f; }
            int i = 0;
            for (; i + 4 <= dg; i += 4) {
                #pragma unroll
                for (int jj = 0; jj < 4; ++jj) {
                    const unsigned r = rec4[(size_t)(st + i + jj)];
                    const float u2 = (float)((r >> 17) & 0x7Fu) * UQS;
                    const uint2 q2 = f8v[(size_t)(r & 0x1FFFFu) * 8 + f];
                    const f32x2 a0 = __builtin_amdgcn_cvt_pk_f32_fp8((int)q2.x, false);
                    const f32x2 a1 = __builtin_amdgcn_cvt_pk_f32_fp8((int)q2.x, true);
                    const f32x2 b0 = __builtin_amdgcn_cvt_pk_f32_fp8((int)q2.y, false);
                    const f32x2 b1 = __builtin_amdgcn_cvt_pk_f32_fp8((int)q2.y, true);
                    const float v0 = a0[0], v1 = a0[1], v2 = a1[0], v3 = a1[1];
                    const float v4 = b0[0], v5 = b0[1], v6 = b1[0], v7 = b1[1];
                    sum[0] += v0; sum[1] += v1; sum[2] += v2; sum[3] += v3;
                    sum[4] += v4; sum[5] += v5; sum[6] += v6; sum[7] += v7;
                    smu[0] = fmaf(u2, v0, smu[0]); smu[1] = fmaf(u2, v1, smu[1]);
                    smu[2] = fmaf(u2, v2, smu[2]); smu[3] = fmaf(u2, v3, smu[3]);
                    smu[4] = fmaf(u2, v4, smu[4]); smu[5] = fmaf(u2, v5, smu[5]);
                    smu[6] = fmaf(u2, v6, smu[6]); smu[7] = fmaf(u2, v7, smu[7]);
                }
            }
            for (; i < dg; ++i) {
                const unsigned r = rec4[(size_t)(st + i)];
                const float u2 = (float)((r >> 17) & 0x7Fu) * UQS;
                const uint2 q2 = f8v[(size_t)(r & 0x1FFFFu) * 8 + f];
                const f32x2 a0 = __builtin_amdgcn_cvt_pk_f32_fp8((int)q2.x, false);
                const f32x2 a1 = __builtin_amdgcn_cvt_pk_f32_fp8((int)q2.x, true);
                const f32x2 b0 = __builtin_amdgcn_cvt_pk_f32_fp8((int)q2.y, false);
                const f32x2 b1 = __builtin_amdgcn_cvt_pk_f32_fp8((int)q2.y, true);
                const float v0 = a0[0], v1 = a0[1], v2 = a1[0], v3 = a1[1];
                const float v4 = b0[0], v5 = b0[1], v6 = b1[0], v7 = b1[1];
                sum[0] += v0; sum[1] += v1; sum[2] += v2; sum[3] += v3;
                sum[4] += v4; sum[5] += v5; sum[6] += v6; sum[7] += v7;
                smu[0] = fmaf(u2, v0, smu[0]); smu[1] = fmaf(u2, v1, smu[1]);
                smu[2] = fmaf(u2, v2, smu[2]); smu[3] = fmaf(u2, v3, smu[3]);
                smu[4] = fmaf(u2, v4, smu[4]); smu[5] = fmaf(u2, v5, smu[5]);
                smu[6] = fmaf(u2, v6, smu[6]); smu[7] = fmaf(u2, v7, smu[7]);
            }
            const float inv = 1.0f / fmaxf((float)dg, 1.0f);
            s16x8 p0, p1;
            #pragma unroll
            for (int k = 0; k < 8; ++k) {
                p0[k] = (short)f2bf((sum[k] - smu[k]) * inv);
                p1[k] = (short)f2bf(smu[k] * inv);
            }
            const int swz = (nlq & 7) << 4;
            *(s16x8*)(sW + nlq * 256 + ((f * 16) ^ swz))         = p0;
            *(s16x8*)(sW + nlq * 256 + 128 + ((f * 16) ^ swz))   = p1;
        }
    }
    // wave-local drain of own DS queue; fence scheduler (guide rule #18).
    asm volatile("s_waitcnt lgkmcnt(0)" ::: "memory");
    __builtin_amdgcn_sched_barrier(0);

    // ---- MFMA phase: this wave's 16 rows ----
    const int kg = l >> 4;
    const int rl = l & 15;                    // row within wave tile
    const int swzr = (rl & 7) << 4;
    int grow = base + rl;
    if (grow >= NN) grow = NN - 1;
    const s16x8* __restrict__ Xr = (const s16x8*)(featb + (size_t)grow * 64);

    s16x8 af[6];
    #pragma unroll
    for (int kb = 0; kb < 2; ++kb)
        af[kb] = *(const s16x8*)(sW + rl * 256 + ((kb * 64 + kg * 16) ^ swzr));
    #pragma unroll
    for (int kb = 2; kb < 4; ++kb)
        af[kb] = *(const s16x8*)(sW + rl * 256 + 128 + (((kb - 2) * 64 + kg * 16) ^ swzr));
    af[4] = Xr[kg];
    af[5] = Xr[4 + kg];

    if (LAYER == 1) {
        f32x4 acc[4];
        #pragma unroll
        for (int ct = 0; ct < 4; ++ct) acc[ct] = (f32x4){0.f, 0.f, 0.f, 0.f};
        #pragma unroll
        for (int kb = 0; kb < 6; ++kb) {
            #pragma unroll
            for (int ct = 0; ct < 4; ++ct) {
                acc[ct] = __builtin_amdgcn_mfma_f32_16x16x32_bf16(
                    af[kb], Bp[(kb * 4 + ct) * 64 + l], acc[ct], 0, 0, 0);
            }
        }
        const int orow0 = base + kg * 4;
        #pragma unroll
        for (int ct = 0; ct < 4; ++ct) {
            const float bv = bias[ct * 16 + (l & 15)];
            #pragma unroll
            for (int j = 0; j < 4; ++j) {
                float v = acc[ct][j] + bv;
                v = (v > 0.f) ? v : (__expf(v) - 1.f);
                const int r2 = orow0 + j;
                if (r2 < NN) {
                    hbf[(size_t)r2 * 64 + ct * 16 + (l & 15)] = f2bf(v);
                    const int e8 = __builtin_amdgcn_cvt_pk_fp8_f32(v, v, 0, false);
                    h8[(size_t)r2 * 64 + ct * 16 + (l & 15)] = (unsigned char)(e8 & 0xFF);
                }
            }
        }
    } else {
        f32x4 acc[3];
        #pragma unroll
        for (int ct = 0; ct < 3; ++ct) acc[ct] = (f32x4){0.f, 0.f, 0.f, 0.f};
        #pragma unroll
        for (int kb = 0; kb < 6; ++kb) {
            #pragma unroll
            for (int ct = 0; ct < 3; ++ct) {
                acc[ct] = __builtin_amdgcn_mfma_f32_16x16x32_bf16(
                    af[kb], Bp[(kb * 3 + ct) * 64 + l], acc[ct], 0, 0, 0);
            }
        }
        const int col = l & 15;
        const float b0 = bias[col], b1v = bias[16 + col];
        const float b2v = (col < 8) ? bias[32 + col] : 0.f;
        #pragma unroll
        for (int j = 0; j < 4; ++j) {
            const float v0 = acc[0][j] + b0;
            const float v1 = acc[1][j] + b1v;
            const float v2 = (col < 8) ? (acc[2][j] + b2v) : -3.0e38f;
            float m = fmaxf(fmaxf(v0, v1), v2);
            #pragma unroll
            for (int off = 1; off < 16; off <<= 1) m = fmaxf(m, __shfl_xor(m, off, 64));
            float s = __expf(v0 - m) + __expf(v1 - m) + ((col < 8) ? __expf(v2 - m) : 0.f);
            #pragma unroll
            for (int off = 1; off < 16; off <<= 1) s += __shfl_xor(s, off, 64);
            const float lse = m + __logf(s);
            const int r2 = base + kg * 4 + j;
            if (r2 < NN) {
                float* __restrict__ orow = out + (size_t)r2 * 40;
                orow[col]      = v0 - lse;
                orow[16 + col] = v1 - lse;
                if (col < 8) orow[32 + col] = v2 - lse;
            }
        }
    }
}

// ---------------------------------------------------------------------------
extern "C" void kernel_launch(void* const* d_in, const int* in_sizes, int n_in,
                              void* d_out, int out_size, void* d_ws, size_t ws_size,
                              hipStream_t stream) {
    const float* x     = (const float*)d_in[0];
    const int*   ei    = (const int*)  d_in[1];
    const float* u     = (const float*)d_in[2];
    const float* W1    = (const float*)d_in[3];
    const float* root1 = (const float*)d_in[4];
    const float* b1    = (const float*)d_in[5];
    const float* W2    = (const float*)d_in[6];
    const float* root2 = (const float*)d_in[7];
    const float* b2    = (const float*)d_in[8];
    float*       out   = (float*)d_out;

    const int* src = ei;
    const int* dst = ei + NE;

    // ws layout (padded bins: brec4/rec4 sized NBINS*BCAP, 4B records)
    char* p = (char*)d_ws;
    int* binCur   = (int*)p;  p += 4 * 512;
    int* deg      = (int*)p;  p += (size_t)4 * NN;
    int* rowstart = (int*)p;  p += (size_t)4 * NN;
    unsigned* brec4 = (unsigned*)p;  p += (size_t)4 * NBINS * BCAP;
    unsigned* rec4  = (unsigned*)p;  p += (size_t)4 * NBINS * BCAP;
    unsigned short* xbf = (unsigned short*)p;  p += (size_t)2 * NN * 64;
    unsigned short* hbf = (unsigned short*)p;  p += (size_t)2 * NN * 64;
    unsigned* x8  = (unsigned*)p;  p += (size_t)4 * NN * 16;
    unsigned char* h8 = (unsigned char*)p;  p += (size_t)NN * 64;
    unsigned short* Bp1 = (unsigned short*)p;  p += (size_t)2 * 6 * 4 * 64 * 8;
    unsigned short* Bp2 = (unsigned short*)p;  p += (size_t)2 * 6 * 3 * 64 * 8;

    hipMemsetAsync(binCur, 0, 4 * 512, stream);

    prep_p3_kernel<<<EB + CVT_B + 11, 256, 0, stream>>>(
        src, dst, u, binCur, brec4,
        x, xbf, x8, W1, root1, Bp1, W2, root2, Bp2);
    p4_final_kernel<<<NBINS, 256, 0, stream>>>(brec4, binCur, deg, rowstart, rec4);

    const int NWB = (NN + 15) / 16;   // one wave (16 nodes) per block
    fused_kernel<1><<<NWB, 64, 0, stream>>>(rowstart, deg, rec4, x8, xbf,
                                            (const s16x8*)Bp1, b1, hbf, h8, nullptr);
    fused_kernel<2><<<NWB, 64, 0, stream>>>(rowstart, deg, rec4, (const unsigned*)h8, hbf,
                                            (const s16x8*)Bp2, b2, nullptr, nullptr, out);
}